// Round 2
// baseline (513.278 us; speedup 1.0000x reference)
//
#include <hip/hip_runtime.h>
#include <math.h>

// OmniRobotPhysics: B=8192 independent trajectories, T=1024 sequential steps.
// One thread per trajectory; 128 wave64 total (half the CUs get 1 wave).
// R3 -> R4 changes (theory: 64-way-scattered global loads/stores dominate,
// ~240 cy/step of memory-pipe occupancy serialized via vmcnt backpressure):
//  - STORES: per-chunk LDS transpose. Compute writes 6 floats/step to
//    outbuf[traj][stride 97 dwords] (odd stride -> conflict-free), then the
//    wave cooperatively stores 64 trajectories x 384 B with float3 lanes
//    (2 rows/instr, 32 instrs/chunk, contiguous) instead of 48 scattered
//    float2 stores.
//  - LOADS: cooperative coalesced float3 loads (4 rows/instr, 16/chunk) into
//    registers, async-STAGE split: issue at chunk start, ds_write into the
//    double-buffered inbuf AFTER the 16-step compute (vmcnt wait hidden).
//    Per-lane compute reads inbuf[lane][stride 49] (odd -> conflict-free).
//  - VALU trims: copysign folds sgn+mul into v_bfi; 1/M,1/I folded into
//    force constants; theta wrap via rint (3 instrs).

#define MASS_F 2.8f
#define DT_F 0.016f

// F F^T entries (angles {60,130,230,300} deg, R=0.09):
#define M00_F 2.6736481776669306f
#define M11_F 1.3263518223330697f
#define M12_F (-0.025701769743577074f)
#define M22_F 0.0324f

#define PI_F 3.14159265358979323846f
#define TWO_PI_F 6.28318530717958647692f
#define INV_TWO_PI_F 0.15915494309189533577f

#define CHUNK 16
#define IN_STRIDE 49    // dwords per trajectory row in inbuf (48 data + 1 pad, odd)
#define OUT_STRIDE 97   // dwords per trajectory row in outbuf (96 data + 1 pad, odd)

__device__ __forceinline__ float softplus_f(float x) {
    float ax = fabsf(x);
    return fmaxf(x, 0.0f) + log1pf(expf(-ax));
}

__device__ __forceinline__ float sgn_f(float v) {
    return (v > 0.0f ? 1.0f : 0.0f) - (v < 0.0f ? 1.0f : 0.0f);
}

// Full-range sin/cos: used once for th0 (and in the generic tail).
__device__ __forceinline__ void fast_sincos(float th, float* sp, float* cp) {
    const float INV_PIO2 = 0.63661977236758134f;
    const float PIO2_HI  = 1.57079637050628662109375f;
    const float PIO2_LO  = -4.37113900018624283e-8f;
    float kf = rintf(th * INV_PIO2);
    int   k  = (int)kf;
    float r  = fmaf(-kf, PIO2_HI, th);
    r        = fmaf(-kf, PIO2_LO, r);
    float r2 = r * r;
    float ps = fmaf(r2, 2.7183114e-6f, -1.9515296e-4f);
    ps = fmaf(r2, ps, 8.3333310e-3f);
    ps = fmaf(r2, ps, -1.6666667e-1f);
    float sr = fmaf(r * r2, ps, r);
    float pc = fmaf(r2, 2.4760495e-5f, -1.3888889e-3f);
    pc = fmaf(r2, pc, 4.1666668e-2f);
    pc = fmaf(r2, pc, -0.5f);
    float cr = fmaf(r2, pc, 1.0f);
    int n = k & 3;
    float s = (n == 0) ? sr : (n == 1) ? cr : (n == 2) ? -sr : -cr;
    float c = (n == 0) ? cr : (n == 1) ? -sr : (n == 2) ? -cr : sr;
    *sp = s;
    *cp = c;
}

struct Coef {
    // mass-folded: A*m = A/M etc.;  inertia-folded for torque row
    float A00m, A11m, A12m, A22i, A12i;
    float dv0m, dv1m, dv2i;
    float dc0m, dc1m, dc2i;
    float dxI, dyI;      // dx*M/I, dy*M/I  (al = Tz' - dxI*Fy' + dyI*Fx')
    float dx, dy;
};

// Coalesced load of one 16-step cmd chunk for the wave's 64 trajectories.
// Instruction i covers rows 4i..4i+3 (16 lanes x 12 B = one 192-B row each).
__device__ __forceinline__ void load_cmd_chunk(const float3* __restrict__ cmd3,
                                               int B0, int B, int T, int ch,
                                               int lane, float3 (&pf)[16]) {
    const int rq = lane >> 4, m = lane & 15;
    #pragma unroll
    for (int i = 0; i < 16; ++i) {
        int rg = B0 + 4 * i + rq;
        if (rg >= B) rg = B - 1;
        pf[i] = cmd3[(size_t)rg * T + (size_t)ch * CHUNK + m];
    }
}

__device__ __forceinline__ void write_cmd_chunk(float* __restrict__ inrow,
                                                int lane, const float3 (&pf)[16]) {
    const int rq = lane >> 4, m = lane & 15;
    #pragma unroll
    for (int i = 0; i < 16; ++i) {
        *reinterpret_cast<float3*>(&inrow[(4 * i + rq) * IN_STRIDE + 3 * m]) = pf[i];
    }
}

__global__ __launch_bounds__(64, 1)
void omni_robot_kernel(const float* __restrict__ init_state,   // (B, 6)
                       const float* __restrict__ cmd_all,      // (B, T, 3)
                       const float* __restrict__ com_offset,   // (2,)
                       const float* __restrict__ inertia_p,    // (1,)
                       const float* __restrict__ gain_p,       // (1,)
                       const float* __restrict__ grip_p,       // (1,)
                       const float* __restrict__ drag_v_p,     // (3,)
                       const float* __restrict__ drag_c_p,     // (3,)
                       float* __restrict__ out,                // (B, T+1, 6)
                       int B, int T)
{
    __shared__ float inbuf[2][64 * IN_STRIDE];   // 2 x 12.5 KB
    __shared__ float outbuf[64 * OUT_STRIDE];    // 24.8 KB

    const int lane = threadIdx.x;        // block = 1 wave
    const int B0   = blockIdx.x * 64;
    const int b    = B0 + lane;
    const int bc   = (b < B) ? b : (B - 1);

    const float inertia = softplus_f(inertia_p[0]) + 1e-4f;
    const float gain    = softplus_f(gain_p[0]);
    const float grip    = softplus_f(grip_p[0]);
    const float inv_mass    = 1.0f / MASS_F;
    const float inv_inertia = 1.0f / inertia;

    Coef K;
    K.A00m = (gain * M00_F + grip) * inv_mass;
    K.A11m = (gain * M11_F + grip) * inv_mass;
    K.A12m = (gain * M12_F) * inv_mass;
    K.A12i = (gain * M12_F) * inv_inertia;
    K.A22i = (gain * M22_F + grip) * inv_inertia;
    K.dv0m = softplus_f(drag_v_p[0]) * inv_mass;
    K.dv1m = softplus_f(drag_v_p[1]) * inv_mass;
    K.dv2i = softplus_f(drag_v_p[2]) * inv_inertia;
    K.dc0m = softplus_f(drag_c_p[0]) * inv_mass;
    K.dc1m = softplus_f(drag_c_p[1]) * inv_mass;
    K.dc2i = softplus_f(drag_c_p[2]) * inv_inertia;
    K.dx   = com_offset[0];
    K.dy   = com_offset[1];
    K.dxI  = K.dx * MASS_F * inv_inertia;
    K.dyI  = K.dy * MASS_F * inv_inertia;

    const float* st = init_state + (size_t)bc * 6;
    float x  = st[0];
    float y  = st[1];
    float th = st[2];
    float vx = st[3];
    float vy = st[4];
    float om = st[5];

    float* __restrict__ o = out + (size_t)bc * (size_t)(T + 1) * 6;
    if (b < B) {
        ((float2*)o)[0] = make_float2(x, y);
        ((float2*)o)[1] = make_float2(th, vx);
        ((float2*)o)[2] = make_float2(vy, om);
    }

    // initial frame (once, off the recurrence)
    float cth, sth;
    fast_sincos(th, &sth, &cth);
    float vxb = fmaf(vx, cth, vy * sth);
    float vyb = fmaf(vy, cth, -vx * sth);

    const float3* __restrict__ cmd3 = reinterpret_cast<const float3*>(cmd_all);
    const int nch = T / CHUNK;

    if (nch > 0) {
        float3 pf[16];
        // prologue: stage chunk 0
        load_cmd_chunk(cmd3, B0, B, T, 0, lane, pf);
        write_cmd_chunk(&inbuf[0][0], lane, pf);
        int cur = 0;

        for (int ch = 0; ch < nch; ++ch) {
            // 1) issue coalesced prefetch for next chunk (consumed after compute)
            const int pfch = (ch + 1 < nch) ? (ch + 1) : (nch - 1);
            load_cmd_chunk(cmd3, B0, B, T, pfch, lane, pf);

            // 2) 16 compute steps from inbuf[cur], results into outbuf (LDS)
            const float* __restrict__ urow = &inbuf[cur][lane * IN_STRIDE];
            float* __restrict__ orow = &outbuf[lane * OUT_STRIDE];
            #pragma unroll
            for (int j = 0; j < CHUNK; ++j) {
                const float3 u = *reinterpret_cast<const float3*>(&urow[3 * j]);

                const float ex = u.x - vxb;
                const float ey = u.y - vyb;
                const float ez = u.z - om;

                // mass/inertia-folded forces; coulomb term via copysign (v_bfi)
                const float Fx = fmaf(K.A00m, ex, -fmaf(K.dv0m, vxb, copysignf(K.dc0m, vxb)));
                const float Fy = fmaf(K.A11m, ey, fmaf(K.A12m, ez, -fmaf(K.dv1m, vyb, copysignf(K.dc1m, vyb))));
                const float Tz = fmaf(K.A12i, ey, fmaf(K.A22i, ez, -fmaf(K.dv2i, om, copysignf(K.dc2i, om))));

                const float al  = fmaf(K.dyI, Fx, fmaf(-K.dxI, Fy, Tz));
                const float om2 = om * om;

                const float axb = fmaf(-al, K.dy, fmaf(-om2, K.dx, Fx));
                const float ayb = fmaf( al, K.dx, fmaf(-om2, K.dy, Fy));

                const float nom = fmaf(al, DT_F, om);
                const float wx  = fmaf(axb, DT_F, vxb);   // new vel, OLD body frame
                const float wy  = fmaf(ayb, DT_F, vyb);

                // rotate into new frame: dth = nom*DT (small; damped dynamics)
                const float dth = nom * DT_F;
                const float d2  = dth * dth;
                float sp = fmaf(d2, 8.3333333e-3f, -1.6666667e-1f);
                sp = fmaf(d2, sp, 1.0f);
                const float sd = dth * sp;                       // sin(dth)
                const float cp = fmaf(d2, 4.1666667e-2f, -0.5f);
                const float cd = fmaf(d2, cp, 1.0f);             // cos(dth)

                const float nvxb = fmaf(cd, wx,  sd * wy);       // R(-dth) * w
                const float nvyb = fmaf(cd, wy, -sd * wx);

                // world-frame outputs (OLD c,s: v' = R(th) * w)
                const float nvx = fmaf(cth, wx, -(sth * wy));
                const float nvy = fmaf(sth, wx,  cth * wy);

                // advance (c,s); 1 Newton renorm step
                float nc = fmaf(cth, cd, -(sth * sd));
                float ns = fmaf(sth, cd,  cth * sd);
                const float rn = fmaf(-0.5f, fmaf(nc, nc, ns * ns), 1.5f);
                nc *= rn;
                ns *= rn;

                x = fmaf(nvx, DT_F, x);
                y = fmaf(nvy, DT_F, y);
                float nth = th + dth;
                nth = fmaf(-rintf(nth * INV_TWO_PI_F), TWO_PI_F, nth);

                vxb = nvxb; vyb = nvyb; om = nom; th = nth; cth = nc; sth = ns;

                float* ot = orow + 6 * j;
                ot[0] = x;   ot[1] = y;   ot[2] = nth;
                ot[3] = nvx; ot[4] = nvy; ot[5] = nom;
            }

            // 3) park prefetched cmd into the other inbuf (vmcnt wait lands here,
            //    ~1900 cy after issue -> hidden)
            write_cmd_chunk(&inbuf[cur ^ 1][0], lane, pf);

            // 4) coalesced transpose-store: 2 trajectory rows (384 B each) per
            //    instruction, float3 lanes
            {
                const int rh = lane >> 5, m2 = lane & 31;
                const size_t tbase = (size_t)(ch * CHUNK + 1) * 6 + 3 * m2;
                #pragma unroll
                for (int i = 0; i < 32; ++i) {
                    const int r = 2 * i + rh;
                    const float3 v = *reinterpret_cast<const float3*>(
                        &outbuf[r * OUT_STRIDE + 3 * m2]);
                    const int rg = B0 + r;
                    if (rg < B) {
                        *reinterpret_cast<float3*>(
                            out + (size_t)rg * (size_t)(T + 1) * 6 + tbase) = v;
                    }
                }
            }

            cur ^= 1;
        }
    }

    // generic tail (T % CHUNK != 0); dead for T=1024. World-frame scalar loop.
    if (nch * CHUNK < T && b < B) {
        const float* __restrict__ cmd = cmd_all + (size_t)b * T * 3;
        vx = fmaf(cth, vxb, -sth * vyb);
        vy = fmaf(sth, vxb,  cth * vyb);
        for (int t = nch * CHUNK; t < T; ++t) {
            const float u0 = cmd[3 * t + 0];
            const float u1 = cmd[3 * t + 1];
            const float u2 = cmd[3 * t + 2];
            float c, s;
            fast_sincos(th, &s, &c);
            const float vxb_t = vx * c + vy * s;
            const float vyb_t = vy * c - vx * s;
            const float ex = u0 - vxb_t;
            const float ey = u1 - vyb_t;
            const float ez = u2 - om;
            const float Fx = fmaf(K.A00m, ex, -fmaf(K.dv0m, vxb_t, copysignf(K.dc0m, vxb_t)));
            const float Fy = fmaf(K.A11m, ey, fmaf(K.A12m, ez, -fmaf(K.dv1m, vyb_t, copysignf(K.dc1m, vyb_t))));
            const float Tz = fmaf(K.A12i, ey, fmaf(K.A22i, ez, -fmaf(K.dv2i, om, copysignf(K.dc2i, om))));
            const float al  = fmaf(K.dyI, Fx, fmaf(-K.dxI, Fy, Tz));
            const float om2 = om * om;
            const float axb = fmaf(-al, K.dy, fmaf(-om2, K.dx, Fx));
            const float ayb = fmaf( al, K.dx, fmaf(-om2, K.dy, Fy));
            const float axw = axb * c - ayb * s;
            const float ayw = axb * s + ayb * c;
            vx = vx + axw * DT_F;
            vy = vy + ayw * DT_F;
            om = om + al * DT_F;
            x  = x + vx * DT_F;
            y  = y + vy * DT_F;
            th = th + om * DT_F;
            th = fmaf(-rintf(th * INV_TWO_PI_F), TWO_PI_F, th);
            float* ot = o + (size_t)(t + 1) * 6;
            ((float2*)ot)[0] = make_float2(x, y);
            ((float2*)ot)[1] = make_float2(th, vx);
            ((float2*)ot)[2] = make_float2(vy, om);
        }
    }
}

extern "C" void kernel_launch(void* const* d_in, const int* in_sizes, int n_in,
                              void* d_out, int out_size, void* d_ws, size_t ws_size,
                              hipStream_t stream) {
    const float* init_state = (const float*)d_in[0];
    const float* cmd        = (const float*)d_in[1];
    const float* com_offset = (const float*)d_in[2];
    const float* inertia_p  = (const float*)d_in[3];
    const float* gain_p     = (const float*)d_in[4];
    const float* grip_p     = (const float*)d_in[5];
    const float* drag_v_p   = (const float*)d_in[6];
    const float* drag_c_p   = (const float*)d_in[7];
    float* out = (float*)d_out;

    const int B = in_sizes[0] / 6;
    const int T = in_sizes[1] / (3 * B);

    const int block = 64;
    const int grid = (B + block - 1) / block;
    hipLaunchKernelGGL(omni_robot_kernel, dim3(grid), dim3(block), 0, stream,
                       init_state, cmd, com_offset, inertia_p, gain_p, grip_p,
                       drag_v_p, drag_c_p, out, B, T);
}